// Round 10
// baseline (438.478 us; speedup 1.0000x reference)
//
#include <hip/hip_runtime.h>
#include <cmath>

// PhaseAwareClassifier on MI355X — R27: 32-col waves + 2-bank pipeline at
// 256-thr (the VGPR budget that allows it).
// Allocator model (R19/R22/R24/R25/R26): total VGPR+AGPR budget ~=
// 512 / waves-per-SIMD-enforced-by-block-geometry. 512-thr -> 256 total
// (R26's ~350-demand pipeline spilled 94 regs -> 739MB scratch). 256-thr
// with (256,1) -> up to 512 (R22: 196 clean; m08: no spill through 450).
// Levers combined here:
//  1) 32 cols/wave (2 l-values): A-frags amortized over 2x output ->
//     440 reads/step/image vs R25's 800. Needs acc=144 regs -> only
//     possible at the 512 budget.
//  2) 2-bank kt pipeline (R26's sequence, budget-safe now): LOADX(k0),
//     LOADY(k1), M(k0), LOADX(k2), M(k1), LOADY(k3), M(k2), LOADX(k4),
//     M(k3), M(k4). Each 22-read burst hides under the 72-MFMA block
//     (~360 cyc). sched_barrier(0) pins loads above MFMAs.
//  3) 1 wave/SIMD: TLP replaced by ILP. R22 (no pipeline) was the control.
// Demand ~345 (acc 144 AGPR + banks 176 + misc) << 512. Bit-exact: per-acc
// MFMA chain kt-ascending, same CPAIR order, epilogue/inj float sequences
// identical (absmax 0.0078125 since R17). t=1 kt<2, t=9 tiles-7,8 kept.
// Zero barriers after staging; shuffle energy; 4 images sequential.
// LDS: conn 82,944 + OBP 73,728 + gsp 576 = 157,248 B -> 1 block/CU.

#define NSTEPS  10
#define INJ_ST  4
#define MT      144          // padded M (9 tiles of 16)

typedef __bf16 bf16x8 __attribute__((ext_vector_type(8)));
typedef __bf16 bf16x4 __attribute__((ext_vector_type(4)));
typedef short  short8 __attribute__((ext_vector_type(8)));
typedef float  f32x4  __attribute__((ext_vector_type(4)));

// workspace layout (float offsets)
#define WS_MAX    0          // 1      enc_max (uint-ordered float)
#define WS_ENERGY 64         // 1280   energy[b][10]
#define WS_GSP    2048       // 144    g2q[j] = -0.5*log2(e)*softplus(gain)
#define WS_CONN   4096       // 2 bf16 mats [20][144][8] chunked: Cr, Ci

// fused prep: blocks 0..97 = image absmax; blocks 98.. = conn + gsp tables
__global__ void k_pre(const float* __restrict__ img,
                      const float* __restrict__ cr, const float* __restrict__ ci,
                      const float* __restrict__ phase, const float* __restrict__ gain,
                      float* ws) {
    if (blockIdx.x < 98) {
        __shared__ float sm[256];
        float v = 0.f;
        for (int i = blockIdx.x * 256 + threadIdx.x; i < 128 * 28 * 28; i += 98 * 256)
            v = fmaxf(v, fabsf(img[i]));
        sm[threadIdx.x] = v;
        __syncthreads();
        for (int s = 128; s > 0; s >>= 1) {
            if (threadIdx.x < s) sm[threadIdx.x] = fmaxf(sm[threadIdx.x], sm[threadIdx.x + s]);
            __syncthreads();
        }
        if (threadIdx.x == 0)
            atomicMax((unsigned int*)(ws + WS_MAX), __float_as_uint(sm[0]));
        return;
    }
    int i = (blockIdx.x - 98) * 256 + threadIdx.x;
    __bf16* Cb = (__bf16*)(ws + WS_CONN);
    const int NCE = MT * 160;              // 23040 (m,k) pairs
    if (i < NCE) {
        int m = i / 160, k = i % 160;
        float vr = 0.f, vi = 0.f;
        if (m < 131 && k < 131) {
            float a = cr[k * 131 + m], b = ci[k * 131 + m];
            float ph = phase[m];
            float cp = cosf(ph), sp = sinf(ph);
            vr = a * cp - b * sp;
            vi = a * sp + b * cp;
        }
        int ca = ((k >> 3) * MT + m) * 8 + (k & 7);    // chunked addr
        Cb[ca]       = (__bf16)vr;
        Cb[NCE + ca] = (__bf16)vi;
    } else if (i < NCE + MT) {
        int j = i - NCE;
        float g = 0.f;
        if (j < 131) {
            float x = gain[j];
            g = (x > 20.f) ? x : log1pf(expf(x));  // softplus
        }
        ws[WS_GSP + j] = g * -0.72134754543f;       // -2*log2(e)*g / 4
    }
}

static __device__ __forceinline__ f32x4 MF(bf16x8 a, bf16x8 b, f32x4 c) {
    return __builtin_amdgcn_mfma_f32_16x16x32_bf16(a, b, c, 0, 0, 0);
}
static __device__ __forceinline__ bf16x8 bneg(bf16x8 a) {
    short8 t = __builtin_bit_cast(short8, a) ^ (short8)(short)0x8000;
    return __builtin_bit_cast(bf16x8, t);
}

// one complex 16x16 tile accumulation; order identical to R17..R26.
#define CPAIR(AR, AI, BR, BI, BNI, P)                                  \
    accr[P] = MF(AR, BR,  accr[P]);                                    \
    accr[P] = MF(AI, BNI, accr[P]);                                    \
    acci[P] = MF(AR, BI,  acci[P]);                                    \
    acci[P] = MF(AI, BR,  acci[P]);

// load one kt's full operand bank: 4 B frags (2 n-tiles) + 18 A frags
#define LOADK(BR0, BI0, BR1, BI1, AR, AI, RK) do {                     \
    const int rk_ = (RK);                                              \
    const int bb_ = (rk_ * 32 + ln15) * 8;                             \
    BR0 = *(const bf16x8*)(OWr + bb_);                                 \
    BI0 = *(const bf16x8*)(OWi + bb_);                                 \
    BR1 = *(const bf16x8*)(OWr + bb_ + 128);                           \
    BI1 = *(const bf16x8*)(OWi + bb_ + 128);                           \
    const int ab_ = (rk_ * MT + ln15) * 8;                             \
    _Pragma("unroll")                                                  \
    for (int m_ = 0; m_ < 9; ++m_) {                                   \
        AR[m_] = *(const bf16x8*)(CrL + ab_ + m_ * 128);               \
        AI[m_] = *(const bf16x8*)(CiL + ab_ + m_ * 128);               \
    }                                                                  \
} while (0)

// consume one bank: 72 MFMAs (9 mt x 2 nt x 4)
#define DOMFMA(BR0, BI0, BR1, BI1, AR, AI) do {                        \
    bf16x8 bn0_ = bneg(BI0);                                           \
    bf16x8 bn1_ = bneg(BI1);                                           \
    _Pragma("unroll")                                                  \
    for (int m_ = 0; m_ < 9; ++m_) {                                   \
        CPAIR(AR[m_], AI[m_], BR0, BI0, bn0_, m_ * 2)                  \
        CPAIR(AR[m_], AI[m_], BR1, BI1, bn1_, m_ * 2 + 1)              \
    }                                                                  \
} while (0)

__global__ __launch_bounds__(256, 1)
void k_main(const float* __restrict__ img, const float* __restrict__ ws,
            float* __restrict__ energy) {
    __shared__ __bf16 CrL[18 * MT * 8];            // 41,472 B
    __shared__ __bf16 CiL[18 * MT * 8];            // 41,472 B
    __shared__ __bf16 OBP[2][4][18 * 32 * 8];      // 73,728 B  [r/i][wave][...]
    __shared__ float  gspL[144];                   // 576 B
    // total 157,248 B -> 1 block/CU, 4 waves = 1/SIMD, 32 cols/wave.

    const int tid  = threadIdx.x;
    const int lane = tid & 63;
    const int ln15 = lane & 15;
    const int quad = lane >> 4;
    const int w    = __builtin_amdgcn_readfirstlane(tid >> 6);  // 0..3
    const int bs   = blockIdx.x & 7;                // col-slice of each image

    __bf16* __restrict__ OWr = &OBP[0][w][0];
    __bf16* __restrict__ OWi = &OBP[1][w][0];

    // injection scaling (identical rounding chain to R20..R26)
    const float mx = ws[WS_MAX];
    const float sc = (mx > 1e-8f) ? (1.02f / mx) : 1.02f;   // 0.85*4*0.3

    // wave w owns l-pair {bs*8 + 2w, +1}; cols (nt,m): nt=l-parity, m=ln15
    float wls[2];
#pragma unroll
    for (int nt = 0; nt < 2; ++nt) {
        int l = (bs * 8 + 2 * w + nt) & 63;
        wls[nt] = 1.0f - fabsf((float)l - 32.0f) * (1.0f / 64.0f);
    }

    // stage conn chunks 0..17 + gsp -> LDS (the ONLY barrier in the kernel)
    {
        const int4* srcR = (const int4*)(ws + WS_CONN);
        const int4* srcI = (const int4*)(ws + WS_CONN + (MT * 160 / 2));
        int4* dstR = (int4*)CrL;
        int4* dstI = (int4*)CiL;
        for (int i = tid; i < 2592; i += 256) { dstR[i] = srcR[i]; dstI[i] = srcI[i]; }
        if (tid < 144) gspL[tid] = ws[WS_GSP + tid];
    }
    __syncthreads();                                // conn + gsp staged

    // ---- 4 images sequentially; waves fully independent hereafter ----
#pragma unroll 1
    for (int it = 0; it < 4; ++it) {
        const int im   = (blockIdx.x >> 3) + 32 * it;
        const int imgb = im * 784 + (ln15 >> 2) * 28 + (ln15 & 3);

        f32x4 accr[18], acci[18];                   // p = mt*2 + nt
#pragma unroll
        for (int p = 0; p < 18; ++p) { accr[p] = (f32x4)0.f; acci[p] = (f32x4)0.f; }

        // injection: rows j<49 (tiles 0..3); one img load feeds both nt
        auto inj_add = [&]() {
#pragma unroll
            for (int mt = 0; mt < 4; ++mt) {
#pragma unroll
                for (int r = 0; r < 4; ++r) {
                    int j = mt * 16 + quad * 4 + r;
                    if (j < 49) {
                        int pi = j / 7, pj = j % 7;
                        float px = img[imgb + pi * 112 + pj * 4];
                        float t  = px * sc;
                        accr[mt * 2 + 0][r] = fmaf(t, wls[0], accr[mt * 2 + 0][r]);
                        accr[mt * 2 + 1][r] = fmaf(t, wls[1], accr[mt * 2 + 1][r]);
                    }
                }
            }
        };

        // epilogue: out = a * tanh(g*|f|)/|f| (0.25 folded), write own OB
        auto epilogue = [&]() {
#pragma unroll
            for (int mt = 0; mt < 9; ++mt) {
                f32x4 g2v = *(const f32x4*)(gspL + mt * 16 + quad * 4);
#pragma unroll
                for (int nt = 0; nt < 2; ++nt) {
                    const int p = mt * 2 + nt;
                    bf16x4 pr, pi;
#pragma unroll
                    for (int r = 0; r < 4; ++r) {
                        float ar = accr[p][r], ai = acci[p][r];
                        float mag2 = fmaf(ar, ar, fmaf(ai, ai, 1.6e-7f));
                        float rsq  = __builtin_amdgcn_rsqf(mag2);
                        float e    = __builtin_amdgcn_exp2f(g2v[r] * (mag2 * rsq));
                        float u    = __builtin_amdgcn_rcpf(1.0f + e);
                        float th   = fmaf(-2.0f, e * u, 1.0f);
                        float scv  = th * rsq;
                        pr[r] = (__bf16)(ar * scv); pi[r] = (__bf16)(ai * scv);
                    }
                    const int off = ((mt * 2 + (quad >> 1)) * 32 + nt * 16 + ln15) * 8
                                  + (quad & 1) * 4;
                    *(bf16x4*)(OWr + off) = pr;
                    *(bf16x4*)(OWi + off) = pi;
                }
            }
        };

        inj_add();                                  // t = 0 (out is zero)
        epilogue();                                 // wave-private, no barrier

        // ---- time loop: zero barriers; 2-bank kt pipeline ----
#pragma unroll 1
        for (int t = 1; t < NSTEPS - 1; ++t) {
#pragma unroll
            for (int p = 0; p < 18; ++p) { accr[p] *= 0.85f; acci[p] *= 0.85f; }
            if (t < INJ_ST) inj_add();

            bf16x8 xbr0, xbi0, xbr1, xbi1, xar[9], xai[9];   // bank X
            bf16x8 ybr0, ybi0, ybr1, ybi1, yar[9], yai[9];   // bank Y
            const int rk4 = (16 + quad > 17) ? 17 : 16 + quad;

            if (t == 1) {
                // out(0) rows >=49 exactly zero -> kt 0,1 only
                LOADK(xbr0, xbi0, xbr1, xbi1, xar, xai, quad);
                LOADK(ybr0, ybi0, ybr1, ybi1, yar, yai, 4 + quad);
                __builtin_amdgcn_sched_barrier(0);
                DOMFMA(xbr0, xbi0, xbr1, xbi1, xar, xai);       // kt0
                __builtin_amdgcn_sched_barrier(0);
                DOMFMA(ybr0, ybi0, ybr1, ybi1, yar, yai);       // kt1
            } else {
                LOADK(xbr0, xbi0, xbr1, xbi1, xar, xai, quad);       // kt0
                LOADK(ybr0, ybi0, ybr1, ybi1, yar, yai, 4 + quad);   // kt1
                __builtin_amdgcn_sched_barrier(0);
                DOMFMA(xbr0, xbi0, xbr1, xbi1, xar, xai);            // kt0
                LOADK(xbr0, xbi0, xbr1, xbi1, xar, xai, 8 + quad);   // kt2
                __builtin_amdgcn_sched_barrier(0);
                DOMFMA(ybr0, ybi0, ybr1, ybi1, yar, yai);            // kt1
                LOADK(ybr0, ybi0, ybr1, ybi1, yar, yai, 12 + quad);  // kt3
                __builtin_amdgcn_sched_barrier(0);
                DOMFMA(xbr0, xbi0, xbr1, xbi1, xar, xai);            // kt2
                LOADK(xbr0, xbi0, xbr1, xbi1, xar, xai, rk4);        // kt4
                __builtin_amdgcn_sched_barrier(0);
                DOMFMA(ybr0, ybi0, ybr1, ybi1, yar, yai);            // kt3
                __builtin_amdgcn_sched_barrier(0);
                DOMFMA(xbr0, xbi0, xbr1, xbi1, xar, xai);            // kt4
            }
            epilogue();                             // wave-private, no barrier
        }

        // ---- t = 9: only rows 121..130 (tiles 7,8) feed energy ----
#pragma unroll
        for (int p = 14; p < 18; ++p) { accr[p] *= 0.85f; acci[p] *= 0.85f; }
#pragma unroll 1
        for (int kt = 0; kt < 5; ++kt) {
            const int kch = kt * 4 + quad;
            const int rk  = (kch > 17) ? 17 : kch;
            const int bb  = (rk * 32 + ln15) * 8;
            bf16x8 br0 = *(const bf16x8*)(OWr + bb);
            bf16x8 bi0 = *(const bf16x8*)(OWi + bb);
            bf16x8 br1 = *(const bf16x8*)(OWr + bb + 128);
            bf16x8 bi1 = *(const bf16x8*)(OWi + bb + 128);
            const int ab = (rk * MT + ln15) * 8;
            bf16x8 ar7 = *(const bf16x8*)(CrL + ab + 7 * 128);
            bf16x8 ai7 = *(const bf16x8*)(CiL + ab + 7 * 128);
            bf16x8 ar8 = *(const bf16x8*)(CrL + ab + 8 * 128);
            bf16x8 ai8 = *(const bf16x8*)(CiL + ab + 8 * 128);
            bf16x8 bn0 = bneg(bi0);
            bf16x8 bn1 = bneg(bi1);
            CPAIR(ar7, ai7, br0, bi0, bn0, 14)
            CPAIR(ar7, ai7, br1, bi1, bn1, 15)
            CPAIR(ar8, ai8, br0, bi0, bn0, 16)
            CPAIR(ar8, ai8, br1, bi1, bn1, 17)
        }

        // ---- energy: per-lane |out|^2, reduce over 16 m-lanes, atomicAdd ----
#pragma unroll
        for (int mt = 7; mt < 9; ++mt) {
#pragma unroll
            for (int nt = 0; nt < 2; ++nt) {
                const int p = mt * 2 + nt;
#pragma unroll
                for (int r = 0; r < 4; ++r) {
                    int j = mt * 16 + quad * 4 + r;
                    if (j >= 121 && j <= 130) {
                        float ar = accr[p][r], ai = acci[p][r];
                        float mag2 = fmaf(ar, ar, fmaf(ai, ai, 1.6e-7f));
                        float rsq  = __builtin_amdgcn_rsqf(mag2);
                        float e    = __builtin_amdgcn_exp2f(gspL[j] * (mag2 * rsq));
                        float u    = __builtin_amdgcn_rcpf(1.0f + e);
                        float th   = fmaf(-2.0f, e * u, 1.0f);
                        float scv  = th * rsq;
                        float orv = ar * scv, oiv = ai * scv;
                        float e2 = orv * orv + oiv * oiv;
                        e2 += __shfl_xor(e2, 1);
                        e2 += __shfl_xor(e2, 2);
                        e2 += __shfl_xor(e2, 4);
                        e2 += __shfl_xor(e2, 8);
                        if (ln15 == 0) atomicAdd(energy + im * 10 + (j - 121), e2);
                    }
                }
            }
        }
    }
}

__global__ void k_readout(const float* __restrict__ ws,
                          const float* __restrict__ W,
                          const float* __restrict__ bias,
                          float* __restrict__ out) {
    int i = blockIdx.x * 256 + threadIdx.x;
    if (i < 1280) {
        int b = i / 10, o = i % 10;
        float s = bias[o];
#pragma unroll
        for (int f = 0; f < 10; ++f) {
            float feat = log1pf(ws[WS_ENERGY + b * 10 + f] + 1e-8f);
            s = fmaf(feat, W[o * 10 + f], s);
        }
        out[i] = s;
    }
}

extern "C" void kernel_launch(void* const* d_in, const int* in_sizes, int n_in,
                              void* d_out, int out_size, void* d_ws, size_t ws_size,
                              hipStream_t stream) {
    const float* images = (const float*)d_in[0];
    const float* conn_r = (const float*)d_in[1];
    const float* conn_i = (const float*)d_in[2];
    const float* phase  = (const float*)d_in[3];
    const float* gain   = (const float*)d_in[4];
    const float* W      = (const float*)d_in[5];
    const float* bias   = (const float*)d_in[6];
    float* ws  = (float*)d_ws;
    float* out = (float*)d_out;

    // zero WS_MAX + energy (floats 0..1343) — stream-ordered, capture-safe
    hipMemsetAsync(ws, 0, (WS_ENERGY + 1280) * sizeof(float), stream);
    hipLaunchKernelGGL(k_pre, dim3(189), dim3(256), 0, stream,
                       images, conn_r, conn_i, phase, gain, ws);
    hipLaunchKernelGGL(k_main, dim3(256), dim3(256), 0, stream,
                       images, ws, ws + WS_ENERGY);
    hipLaunchKernelGGL(k_readout, dim3(5), dim3(256), 0, stream, ws, W, bias, out);
}

// Round 11
// 347.261 us; speedup vs baseline: 1.2627x; 1.2627x over previous
//
#include <hip/hip_runtime.h>
#include <cmath>

// PhaseAwareClassifier on MI355X — R28: traffic-optimal 32-col waves +
// wave-stagger (de-synchronized LDS bursts).
// R27 post-mortem: VGPR pegged at the ARCHITECTURAL 256 max, 403MB scratch.
// acc[144] can't live in AGPRs (decay/inj/epilogue are VALU) -> acc + 2
// banks (176) can never fit 256: double-banked pipelining is register-
// infeasible at 32 cols/wave. Clean points: R25 (16-col, 800 reads/128col,
// 223.5us), R22 (32-col single-bank, 440 reads/128col, 273us = 4x its 74us
// LDS floor). R22's gap = synchronized burst contention: 4 waves issue
// 22-read bursts in lockstep (queue 4x, SIMDs idle) then all MFMA (LDS
// idle). Compiler already emits counted lgkmcnt within a burst; the waste
// is cross-wave phase alignment, and nothing ever re-aligns them.
// R28 = R22 shape + one-time s_sleep ladder (w x ~512 cyc) after staging:
// waves spread across a kt-phase; MFMA of one overlaps loads of others.
// Bit-exact: sleep changes nothing; single-bank kt-ascending chain order
// unchanged since R17 (absmax 0.0078125). 4 img/block + shuffle energy +
// zero t-loop barriers kept from R27. (256,1): R22 proved ~196 VGPR clean.
// LDS: conn 82,944 + OBP 73,728 + gsp 576 = 157,248 B -> 1 block/CU.

#define NSTEPS  10
#define INJ_ST  4
#define MT      144          // padded M (9 tiles of 16)

typedef __bf16 bf16x8 __attribute__((ext_vector_type(8)));
typedef __bf16 bf16x4 __attribute__((ext_vector_type(4)));
typedef short  short8 __attribute__((ext_vector_type(8)));
typedef float  f32x4  __attribute__((ext_vector_type(4)));

// workspace layout (float offsets)
#define WS_MAX    0          // 1      enc_max (uint-ordered float)
#define WS_ENERGY 64         // 1280   energy[b][10]
#define WS_GSP    2048       // 144    g2q[j] = -0.5*log2(e)*softplus(gain)
#define WS_CONN   4096       // 2 bf16 mats [20][144][8] chunked: Cr, Ci

// fused prep: blocks 0..97 = image absmax; blocks 98.. = conn + gsp tables
__global__ void k_pre(const float* __restrict__ img,
                      const float* __restrict__ cr, const float* __restrict__ ci,
                      const float* __restrict__ phase, const float* __restrict__ gain,
                      float* ws) {
    if (blockIdx.x < 98) {
        __shared__ float sm[256];
        float v = 0.f;
        for (int i = blockIdx.x * 256 + threadIdx.x; i < 128 * 28 * 28; i += 98 * 256)
            v = fmaxf(v, fabsf(img[i]));
        sm[threadIdx.x] = v;
        __syncthreads();
        for (int s = 128; s > 0; s >>= 1) {
            if (threadIdx.x < s) sm[threadIdx.x] = fmaxf(sm[threadIdx.x], sm[threadIdx.x + s]);
            __syncthreads();
        }
        if (threadIdx.x == 0)
            atomicMax((unsigned int*)(ws + WS_MAX), __float_as_uint(sm[0]));
        return;
    }
    int i = (blockIdx.x - 98) * 256 + threadIdx.x;
    __bf16* Cb = (__bf16*)(ws + WS_CONN);
    const int NCE = MT * 160;              // 23040 (m,k) pairs
    if (i < NCE) {
        int m = i / 160, k = i % 160;
        float vr = 0.f, vi = 0.f;
        if (m < 131 && k < 131) {
            float a = cr[k * 131 + m], b = ci[k * 131 + m];
            float ph = phase[m];
            float cp = cosf(ph), sp = sinf(ph);
            vr = a * cp - b * sp;
            vi = a * sp + b * cp;
        }
        int ca = ((k >> 3) * MT + m) * 8 + (k & 7);    // chunked addr
        Cb[ca]       = (__bf16)vr;
        Cb[NCE + ca] = (__bf16)vi;
    } else if (i < NCE + MT) {
        int j = i - NCE;
        float g = 0.f;
        if (j < 131) {
            float x = gain[j];
            g = (x > 20.f) ? x : log1pf(expf(x));  // softplus
        }
        ws[WS_GSP + j] = g * -0.72134754543f;       // -2*log2(e)*g / 4
    }
}

static __device__ __forceinline__ f32x4 MF(bf16x8 a, bf16x8 b, f32x4 c) {
    return __builtin_amdgcn_mfma_f32_16x16x32_bf16(a, b, c, 0, 0, 0);
}
static __device__ __forceinline__ bf16x8 bneg(bf16x8 a) {
    short8 t = __builtin_bit_cast(short8, a) ^ (short8)(short)0x8000;
    return __builtin_bit_cast(bf16x8, t);
}

// one complex 16x16 tile accumulation; order identical to R17..R27.
#define CPAIR(AR, AI, BR, BI, BNI, P)                                  \
    accr[P] = MF(AR, BR,  accr[P]);                                    \
    accr[P] = MF(AI, BNI, accr[P]);                                    \
    acci[P] = MF(AR, BI,  acci[P]);                                    \
    acci[P] = MF(AI, BR,  acci[P]);

// load one kt's full operand bank: 4 B frags (2 n-tiles) + 18 A frags
#define LOADK(BR0, BI0, BR1, BI1, AR, AI, RK) do {                     \
    const int rk_ = (RK);                                              \
    const int bb_ = (rk_ * 32 + ln15) * 8;                             \
    BR0 = *(const bf16x8*)(OWr + bb_);                                 \
    BI0 = *(const bf16x8*)(OWi + bb_);                                 \
    BR1 = *(const bf16x8*)(OWr + bb_ + 128);                           \
    BI1 = *(const bf16x8*)(OWi + bb_ + 128);                           \
    const int ab_ = (rk_ * MT + ln15) * 8;                             \
    _Pragma("unroll")                                                  \
    for (int m_ = 0; m_ < 9; ++m_) {                                   \
        AR[m_] = *(const bf16x8*)(CrL + ab_ + m_ * 128);               \
        AI[m_] = *(const bf16x8*)(CiL + ab_ + m_ * 128);               \
    }                                                                  \
} while (0)

// consume one bank: 72 MFMAs (9 mt x 2 nt x 4)
#define DOMFMA(BR0, BI0, BR1, BI1, AR, AI) do {                        \
    bf16x8 bn0_ = bneg(BI0);                                           \
    bf16x8 bn1_ = bneg(BI1);                                           \
    _Pragma("unroll")                                                  \
    for (int m_ = 0; m_ < 9; ++m_) {                                   \
        CPAIR(AR[m_], AI[m_], BR0, BI0, bn0_, m_ * 2)                  \
        CPAIR(AR[m_], AI[m_], BR1, BI1, bn1_, m_ * 2 + 1)              \
    }                                                                  \
} while (0)

__global__ __launch_bounds__(256, 1)
void k_main(const float* __restrict__ img, const float* __restrict__ ws,
            float* __restrict__ energy) {
    __shared__ __bf16 CrL[18 * MT * 8];            // 41,472 B
    __shared__ __bf16 CiL[18 * MT * 8];            // 41,472 B
    __shared__ __bf16 OBP[2][4][18 * 32 * 8];      // 73,728 B  [r/i][wave][...]
    __shared__ float  gspL[144];                   // 576 B
    // total 157,248 B -> 1 block/CU, 4 waves = 1/SIMD, 32 cols/wave.

    const int tid  = threadIdx.x;
    const int lane = tid & 63;
    const int ln15 = lane & 15;
    const int quad = lane >> 4;
    const int w    = __builtin_amdgcn_readfirstlane(tid >> 6);  // 0..3
    const int bs   = blockIdx.x & 7;                // col-slice of each image

    __bf16* __restrict__ OWr = &OBP[0][w][0];
    __bf16* __restrict__ OWi = &OBP[1][w][0];

    // injection scaling (identical rounding chain to R20..R27)
    const float mx = ws[WS_MAX];
    const float sc = (mx > 1e-8f) ? (1.02f / mx) : 1.02f;   // 0.85*4*0.3

    // wave w owns l-pair {bs*8 + 2w, +1}; cols (nt,m): nt=l-parity, m=ln15
    float wls[2];
#pragma unroll
    for (int nt = 0; nt < 2; ++nt) {
        int l = (bs * 8 + 2 * w + nt) & 63;
        wls[nt] = 1.0f - fabsf((float)l - 32.0f) * (1.0f / 64.0f);
    }

    // stage conn chunks 0..17 + gsp -> LDS (the ONLY barrier in the kernel)
    {
        const int4* srcR = (const int4*)(ws + WS_CONN);
        const int4* srcI = (const int4*)(ws + WS_CONN + (MT * 160 / 2));
        int4* dstR = (int4*)CrL;
        int4* dstI = (int4*)CiL;
        for (int i = tid; i < 2592; i += 256) { dstR[i] = srcR[i]; dstI[i] = srcI[i]; }
        if (tid < 144) gspL[tid] = ws[WS_GSP + tid];
    }
    __syncthreads();                                // conn + gsp staged

    // ---- wave stagger: spread the 4 waves across ~1 kt-phase so their
    // 22-read LDS bursts interleave with each other's MFMA blocks. One-time
    // cost <=1 us; offset persists (no barriers, identical periods). ----
    if      (w == 1) __builtin_amdgcn_s_sleep(8);   // ~512 cyc
    else if (w == 2) __builtin_amdgcn_s_sleep(16);  // ~1024 cyc
    else if (w == 3) __builtin_amdgcn_s_sleep(24);  // ~1536 cyc

    // ---- 4 images sequentially; waves fully independent hereafter ----
#pragma unroll 1
    for (int it = 0; it < 4; ++it) {
        const int im   = (blockIdx.x >> 3) + 32 * it;
        const int imgb = im * 784 + (ln15 >> 2) * 28 + (ln15 & 3);

        f32x4 accr[18], acci[18];                   // p = mt*2 + nt
#pragma unroll
        for (int p = 0; p < 18; ++p) { accr[p] = (f32x4)0.f; acci[p] = (f32x4)0.f; }

        // injection: rows j<49 (tiles 0..3); one img load feeds both nt
        auto inj_add = [&]() {
#pragma unroll
            for (int mt = 0; mt < 4; ++mt) {
#pragma unroll
                for (int r = 0; r < 4; ++r) {
                    int j = mt * 16 + quad * 4 + r;
                    if (j < 49) {
                        int pi = j / 7, pj = j % 7;
                        float px = img[imgb + pi * 112 + pj * 4];
                        float t  = px * sc;
                        accr[mt * 2 + 0][r] = fmaf(t, wls[0], accr[mt * 2 + 0][r]);
                        accr[mt * 2 + 1][r] = fmaf(t, wls[1], accr[mt * 2 + 1][r]);
                    }
                }
            }
        };

        // epilogue: out = a * tanh(g*|f|)/|f| (0.25 folded), write own OB
        auto epilogue = [&]() {
#pragma unroll
            for (int mt = 0; mt < 9; ++mt) {
                f32x4 g2v = *(const f32x4*)(gspL + mt * 16 + quad * 4);
#pragma unroll
                for (int nt = 0; nt < 2; ++nt) {
                    const int p = mt * 2 + nt;
                    bf16x4 pr, pi;
#pragma unroll
                    for (int r = 0; r < 4; ++r) {
                        float ar = accr[p][r], ai = acci[p][r];
                        float mag2 = fmaf(ar, ar, fmaf(ai, ai, 1.6e-7f));
                        float rsq  = __builtin_amdgcn_rsqf(mag2);
                        float e    = __builtin_amdgcn_exp2f(g2v[r] * (mag2 * rsq));
                        float u    = __builtin_amdgcn_rcpf(1.0f + e);
                        float th   = fmaf(-2.0f, e * u, 1.0f);
                        float scv  = th * rsq;
                        pr[r] = (__bf16)(ar * scv); pi[r] = (__bf16)(ai * scv);
                    }
                    const int off = ((mt * 2 + (quad >> 1)) * 32 + nt * 16 + ln15) * 8
                                  + (quad & 1) * 4;
                    *(bf16x4*)(OWr + off) = pr;
                    *(bf16x4*)(OWi + off) = pi;
                }
            }
        };

        inj_add();                                  // t = 0 (out is zero)
        epilogue();                                 // wave-private, no barrier

        // ---- time loop: zero barriers; single-bank burst kt body ----
#pragma unroll 1
        for (int t = 1; t < NSTEPS - 1; ++t) {
#pragma unroll
            for (int p = 0; p < 18; ++p) { accr[p] *= 0.85f; acci[p] *= 0.85f; }
            if (t < INJ_ST) inj_add();

            // t=1: out(0) rows >=49 exactly zero -> kt 0,1 only.
            const int ktEnd = (t == 1) ? 2 : 5;
            // kch 18,19 remap to chunk 17 (zeros both sides). unroll(1): R15.
#pragma unroll 1
            for (int kt = 0; kt < ktEnd; ++kt) {
                const int kch = kt * 4 + quad;
                const int rk  = (kch > 17) ? 17 : kch;
                bf16x8 br0, bi0, br1, bi1, ar[9], ai[9];
                LOADK(br0, bi0, br1, bi1, ar, ai, rk);
                DOMFMA(br0, bi0, br1, bi1, ar, ai);
            }
            epilogue();                             // wave-private, no barrier
        }

        // ---- t = 9: only rows 121..130 (tiles 7,8) feed energy ----
#pragma unroll
        for (int p = 14; p < 18; ++p) { accr[p] *= 0.85f; acci[p] *= 0.85f; }
#pragma unroll 1
        for (int kt = 0; kt < 5; ++kt) {
            const int kch = kt * 4 + quad;
            const int rk  = (kch > 17) ? 17 : kch;
            const int bb  = (rk * 32 + ln15) * 8;
            bf16x8 br0 = *(const bf16x8*)(OWr + bb);
            bf16x8 bi0 = *(const bf16x8*)(OWi + bb);
            bf16x8 br1 = *(const bf16x8*)(OWr + bb + 128);
            bf16x8 bi1 = *(const bf16x8*)(OWi + bb + 128);
            const int ab = (rk * MT + ln15) * 8;
            bf16x8 ar7 = *(const bf16x8*)(CrL + ab + 7 * 128);
            bf16x8 ai7 = *(const bf16x8*)(CiL + ab + 7 * 128);
            bf16x8 ar8 = *(const bf16x8*)(CrL + ab + 8 * 128);
            bf16x8 ai8 = *(const bf16x8*)(CiL + ab + 8 * 128);
            bf16x8 bn0 = bneg(bi0);
            bf16x8 bn1 = bneg(bi1);
            CPAIR(ar7, ai7, br0, bi0, bn0, 14)
            CPAIR(ar7, ai7, br1, bi1, bn1, 15)
            CPAIR(ar8, ai8, br0, bi0, bn0, 16)
            CPAIR(ar8, ai8, br1, bi1, bn1, 17)
        }

        // ---- energy: per-lane |out|^2, reduce over 16 m-lanes, atomicAdd ----
#pragma unroll
        for (int mt = 7; mt < 9; ++mt) {
#pragma unroll
            for (int nt = 0; nt < 2; ++nt) {
                const int p = mt * 2 + nt;
#pragma unroll
                for (int r = 0; r < 4; ++r) {
                    int j = mt * 16 + quad * 4 + r;
                    if (j >= 121 && j <= 130) {
                        float ar = accr[p][r], ai = acci[p][r];
                        float mag2 = fmaf(ar, ar, fmaf(ai, ai, 1.6e-7f));
                        float rsq  = __builtin_amdgcn_rsqf(mag2);
                        float e    = __builtin_amdgcn_exp2f(gspL[j] * (mag2 * rsq));
                        float u    = __builtin_amdgcn_rcpf(1.0f + e);
                        float th   = fmaf(-2.0f, e * u, 1.0f);
                        float scv  = th * rsq;
                        float orv = ar * scv, oiv = ai * scv;
                        float e2 = orv * orv + oiv * oiv;
                        e2 += __shfl_xor(e2, 1);
                        e2 += __shfl_xor(e2, 2);
                        e2 += __shfl_xor(e2, 4);
                        e2 += __shfl_xor(e2, 8);
                        if (ln15 == 0) atomicAdd(energy + im * 10 + (j - 121), e2);
                    }
                }
            }
        }
    }
}

__global__ void k_readout(const float* __restrict__ ws,
                          const float* __restrict__ W,
                          const float* __restrict__ bias,
                          float* __restrict__ out) {
    int i = blockIdx.x * 256 + threadIdx.x;
    if (i < 1280) {
        int b = i / 10, o = i % 10;
        float s = bias[o];
#pragma unroll
        for (int f = 0; f < 10; ++f) {
            float feat = log1pf(ws[WS_ENERGY + b * 10 + f] + 1e-8f);
            s = fmaf(feat, W[o * 10 + f], s);
        }
        out[i] = s;
    }
}

extern "C" void kernel_launch(void* const* d_in, const int* in_sizes, int n_in,
                              void* d_out, int out_size, void* d_ws, size_t ws_size,
                              hipStream_t stream) {
    const float* images = (const float*)d_in[0];
    const float* conn_r = (const float*)d_in[1];
    const float* conn_i = (const float*)d_in[2];
    const float* phase  = (const float*)d_in[3];
    const float* gain   = (const float*)d_in[4];
    const float* W      = (const float*)d_in[5];
    const float* bias   = (const float*)d_in[6];
    float* ws  = (float*)d_ws;
    float* out = (float*)d_out;

    // zero WS_MAX + energy (floats 0..1343) — stream-ordered, capture-safe
    hipMemsetAsync(ws, 0, (WS_ENERGY + 1280) * sizeof(float), stream);
    hipLaunchKernelGGL(k_pre, dim3(189), dim3(256), 0, stream,
                       images, conn_r, conn_i, phase, gain, ws);
    hipLaunchKernelGGL(k_main, dim3(256), dim3(256), 0, stream,
                       images, ws, ws + WS_ENERGY);
    hipLaunchKernelGGL(k_readout, dim3(5), dim3(256), 0, stream, ws, W, bias, out);
}

// Round 12
// 269.914 us; speedup vs baseline: 1.6245x; 1.2866x over previous
//
#include <hip/hip_runtime.h>
#include <cmath>

// PhaseAwareClassifier on MI355X — R29: R25 baseline + SIMD-pair stagger.
// R28 post-mortem: 32-col @1/SIMD is latency-fatal regardless of stagger
// (332us; stagger tested in wrong regime). Feasibility map is now closed:
//  - 440-read shape (32-col) needs ~232 regs -> only 1 wave/SIMD -> dead.
//  - conn-from-L2: 720KB/step at ~60 B/cyc/CU L2 = 12k cyc > 9.6k LDS. Dead.
//  - best clean config = R25 (16-col x 8 waves, 2/SIMD, 800 reads/step,
//    LDS floor 125us, measured 223.5us).
// R25's untested stall source: all 8 waves burst 20 ds_reads in lockstep
// (identical streams, same A addresses) -> LDS queue 8x-deep then idle;
// SIMD-sharing pairs (w, w+4) stall in phase. R29 = R25 byte-identical
// + waves 4..7 one-time s_sleep(8) (~512cyc ~ half kt-phase) after staging:
// de-syncs each SIMD's pair, splits the burst into two 4-wave groups.
// Offset persists (zero t-loop barriers). Numerically nothing -> absmax
// 0.0078125 bit-identical. If flat: config is saturated at 2/SIMD ->
// roofline call next round.
// LDS: conn 82,944 + OBP 73,728 + gsp 576 = 157,248 B -> 1 block/CU.

#define NSTEPS  10
#define INJ_ST  4
#define MT      144          // padded M (9 tiles of 16)

typedef __bf16 bf16x8 __attribute__((ext_vector_type(8)));
typedef __bf16 bf16x4 __attribute__((ext_vector_type(4)));
typedef short  short8 __attribute__((ext_vector_type(8)));
typedef float  f32x4  __attribute__((ext_vector_type(4)));

// workspace layout (float offsets)
#define WS_MAX    0          // 1      enc_max (uint-ordered float)
#define WS_ENERGY 64         // 1280   energy[b][10]
#define WS_GSP    2048       // 144    g2q[j] = -0.5*log2(e)*softplus(gain)
#define WS_CONN   4096       // 2 bf16 mats [20][144][8] chunked: Cr, Ci

// fused prep: blocks 0..97 = image absmax; blocks 98.. = conn + gsp tables
__global__ void k_pre(const float* __restrict__ img,
                      const float* __restrict__ cr, const float* __restrict__ ci,
                      const float* __restrict__ phase, const float* __restrict__ gain,
                      float* ws) {
    if (blockIdx.x < 98) {
        __shared__ float sm[256];
        float v = 0.f;
        for (int i = blockIdx.x * 256 + threadIdx.x; i < 128 * 28 * 28; i += 98 * 256)
            v = fmaxf(v, fabsf(img[i]));
        sm[threadIdx.x] = v;
        __syncthreads();
        for (int s = 128; s > 0; s >>= 1) {
            if (threadIdx.x < s) sm[threadIdx.x] = fmaxf(sm[threadIdx.x], sm[threadIdx.x + s]);
            __syncthreads();
        }
        if (threadIdx.x == 0)
            atomicMax((unsigned int*)(ws + WS_MAX), __float_as_uint(sm[0]));
        return;
    }
    int i = (blockIdx.x - 98) * 256 + threadIdx.x;
    __bf16* Cb = (__bf16*)(ws + WS_CONN);
    const int NCE = MT * 160;              // 23040 (m,k) pairs
    if (i < NCE) {
        int m = i / 160, k = i % 160;
        float vr = 0.f, vi = 0.f;
        if (m < 131 && k < 131) {
            float a = cr[k * 131 + m], b = ci[k * 131 + m];
            float ph = phase[m];
            float cp = cosf(ph), sp = sinf(ph);
            vr = a * cp - b * sp;
            vi = a * sp + b * cp;
        }
        int ca = ((k >> 3) * MT + m) * 8 + (k & 7);    // chunked addr
        Cb[ca]       = (__bf16)vr;
        Cb[NCE + ca] = (__bf16)vi;
    } else if (i < NCE + MT) {
        int j = i - NCE;
        float g = 0.f;
        if (j < 131) {
            float x = gain[j];
            g = (x > 20.f) ? x : log1pf(expf(x));  // softplus
        }
        ws[WS_GSP + j] = g * -0.72134754543f;       // -2*log2(e)*g / 4
    }
}

static __device__ __forceinline__ f32x4 MF(bf16x8 a, bf16x8 b, f32x4 c) {
    return __builtin_amdgcn_mfma_f32_16x16x32_bf16(a, b, c, 0, 0, 0);
}
static __device__ __forceinline__ bf16x8 bneg(bf16x8 a) {
    short8 t = __builtin_bit_cast(short8, a) ^ (short8)(short)0x8000;
    return __builtin_bit_cast(bf16x8, t);
}

// one complex 16x16 tile accumulation; order identical to R17..R28.
#define CPAIR(AR, AI, BR, BI, BNI, P)                                  \
    accr[P] = MF(AR, BR,  accr[P]);                                    \
    accr[P] = MF(AI, BNI, accr[P]);                                    \
    acci[P] = MF(AR, BI,  acci[P]);                                    \
    acci[P] = MF(AI, BR,  acci[P]);

__global__ __launch_bounds__(512, 2)
void k_main(const float* __restrict__ img, const float* __restrict__ ws,
            float* __restrict__ energy) {
    __shared__ __bf16 CrL[18 * MT * 8];            // 41,472 B
    __shared__ __bf16 CiL[18 * MT * 8];            // 41,472 B
    __shared__ __bf16 OBP[2][8][18 * 16 * 8];      // 73,728 B  [r/i][wave][...]
    __shared__ float  gspL[144];                   // 576 B
    // total 157,248 B -> 1 block/CU, 8 waves = 2/SIMD (hint matches).

    const int tid  = threadIdx.x;
    const int lane = tid & 63;
    const int ln15 = lane & 15;
    const int quad = lane >> 4;
    const int w    = __builtin_amdgcn_readfirstlane(tid >> 6);  // 0..7
    const int bs   = blockIdx.x & 7;                // col-slice of each image

    __bf16* __restrict__ OWr = &OBP[0][w][0];
    __bf16* __restrict__ OWi = &OBP[1][w][0];

    // injection scaling (identical rounding chain to R20..R28)
    const float mx = ws[WS_MAX];
    const float sc = (mx > 1e-8f) ? (1.02f / mx) : 1.02f;   // 0.85*4*0.3

    // wave w owns cols [16w, 16w+16) of its slice: single l-value, m = ln15
    const int   l   = (bs * 8 + w) & 63;
    const float wl  = 1.0f - fabsf((float)l - 32.0f) * (1.0f / 64.0f);

    // stage conn chunks 0..17 + gsp -> LDS (the ONLY barrier in the kernel)
    {
        const int4* srcR = (const int4*)(ws + WS_CONN);
        const int4* srcI = (const int4*)(ws + WS_CONN + (MT * 160 / 2));
        int4* dstR = (int4*)CrL;
        int4* dstI = (int4*)CiL;
        for (int i = tid; i < 2592; i += 512) { dstR[i] = srcR[i]; dstI[i] = srcI[i]; }
        if (tid < 144) gspL[tid] = ws[WS_GSP + tid];
    }
    __syncthreads();                                // conn + gsp staged

    // ---- SIMD-pair stagger: waves 4..7 (the second wave on each SIMD)
    // sleep ~512 cyc once. Splits the 8-wave lockstep LDS burst into two
    // 4-wave phase groups; offset persists (no barriers, equal periods). ----
    if (w >= 4) __builtin_amdgcn_s_sleep(8);

    // ---- 4 images sequentially; waves fully independent hereafter ----
#pragma unroll 1
    for (int it = 0; it < 4; ++it) {
        const int im   = (blockIdx.x >> 3) + 32 * it;
        const int imgb = im * 784 + (ln15 >> 2) * 28 + (ln15 & 3);

        f32x4 accr[9], acci[9];                     // p = mt
#pragma unroll
        for (int p = 0; p < 9; ++p) { accr[p] = (f32x4)0.f; acci[p] = (f32x4)0.f; }

        // injection: rows j<49 (tiles 0..3)
        auto inj_add = [&]() {
#pragma unroll
            for (int mt = 0; mt < 4; ++mt) {
#pragma unroll
                for (int r = 0; r < 4; ++r) {
                    int j = mt * 16 + quad * 4 + r;
                    if (j < 49) {
                        int pi = j / 7, pj = j % 7;
                        float px = img[imgb + pi * 112 + pj * 4];
                        float t  = px * sc;
                        accr[mt][r] = fmaf(t, wl, accr[mt][r]);
                    }
                }
            }
        };

        // epilogue: out = a * tanh(g*|f|)/|f| (0.25 folded), write own OB
        auto epilogue = [&]() {
#pragma unroll
            for (int mt = 0; mt < 9; ++mt) {
                f32x4 g2v = *(const f32x4*)(gspL + mt * 16 + quad * 4);
                bf16x4 pr, pi;
#pragma unroll
                for (int r = 0; r < 4; ++r) {
                    float ar = accr[mt][r], ai = acci[mt][r];
                    float mag2 = fmaf(ar, ar, fmaf(ai, ai, 1.6e-7f));
                    float rsq  = __builtin_amdgcn_rsqf(mag2);
                    float e    = __builtin_amdgcn_exp2f(g2v[r] * (mag2 * rsq));
                    float u    = __builtin_amdgcn_rcpf(1.0f + e);
                    float th   = fmaf(-2.0f, e * u, 1.0f);
                    float scv  = th * rsq;
                    pr[r] = (__bf16)(ar * scv); pi[r] = (__bf16)(ai * scv);
                }
                const int off = ((mt * 2 + (quad >> 1)) * 16 + ln15) * 8
                              + (quad & 1) * 4;
                *(bf16x4*)(OWr + off) = pr;
                *(bf16x4*)(OWi + off) = pi;
            }
        };

        inj_add();                                  // t = 0 (out is zero)
        epilogue();                                 // wave-private, no barrier

        // ---- time loop: zero barriers; burst kt body ----
#pragma unroll 1
        for (int t = 1; t < NSTEPS - 1; ++t) {
#pragma unroll
            for (int p = 0; p < 9; ++p) { accr[p] *= 0.85f; acci[p] *= 0.85f; }
            if (t < INJ_ST) inj_add();

            // t=1: out(0) rows >=49 exactly zero -> kt 0,1 only.
            const int ktEnd = (t == 1) ? 2 : 5;
            // kch 18,19 remap to chunk 17 (zeros both sides). unroll(1): R15.
#pragma unroll 1
            for (int kt = 0; kt < ktEnd; ++kt) {
                const int kch = kt * 4 + quad;
                const int rk  = (kch > 17) ? 17 : kch;
                // ---- load burst: 2 B + 18 A reads, then MFMA block ----
                const int bb  = (rk * 16 + ln15) * 8;
                bf16x8 br = *(const bf16x8*)(OWr + bb);
                bf16x8 bi = *(const bf16x8*)(OWi + bb);
                const int ab = (rk * MT + ln15) * 8;
                bf16x8 ar[9], ai[9];
#pragma unroll
                for (int mt = 0; mt < 9; ++mt) {
                    ar[mt] = *(const bf16x8*)(CrL + ab + mt * 128);
                    ai[mt] = *(const bf16x8*)(CiL + ab + mt * 128);
                }
                bf16x8 bn = bneg(bi);
#pragma unroll
                for (int mt = 0; mt < 9; ++mt) {
                    CPAIR(ar[mt], ai[mt], br, bi, bn, mt)
                }
            }
            epilogue();                             // wave-private, no barrier
        }

        // ---- t = 9: only rows 121..130 (tiles 7,8) feed energy ----
        accr[7] *= 0.85f; acci[7] *= 0.85f;
        accr[8] *= 0.85f; acci[8] *= 0.85f;
#pragma unroll 1
        for (int kt = 0; kt < 5; ++kt) {
            const int kch = kt * 4 + quad;
            const int rk  = (kch > 17) ? 17 : kch;
            const int bb  = (rk * 16 + ln15) * 8;
            bf16x8 br = *(const bf16x8*)(OWr + bb);
            bf16x8 bi = *(const bf16x8*)(OWi + bb);
            const int ab = (rk * MT + ln15) * 8;
            bf16x8 ar7 = *(const bf16x8*)(CrL + ab + 7 * 128);
            bf16x8 ai7 = *(const bf16x8*)(CiL + ab + 7 * 128);
            bf16x8 ar8 = *(const bf16x8*)(CrL + ab + 8 * 128);
            bf16x8 ai8 = *(const bf16x8*)(CiL + ab + 8 * 128);
            bf16x8 bn = bneg(bi);
            CPAIR(ar7, ai7, br, bi, bn, 7)
            CPAIR(ar8, ai8, br, bi, bn, 8)
        }

        // ---- energy: per-lane |out|^2, quad shfl-reduce over 16 cols,
        // one atomicAdd per (j) from lane ln15==0 of the owning quad ----
#pragma unroll
        for (int mt = 7; mt < 9; ++mt) {
#pragma unroll
            for (int r = 0; r < 4; ++r) {
                int j = mt * 16 + quad * 4 + r;
                if (j >= 121 && j <= 130) {
                    float ar = accr[mt][r], ai = acci[mt][r];
                    float mag2 = fmaf(ar, ar, fmaf(ai, ai, 1.6e-7f));
                    float rsq  = __builtin_amdgcn_rsqf(mag2);
                    float e    = __builtin_amdgcn_exp2f(gspL[j] * (mag2 * rsq));
                    float u    = __builtin_amdgcn_rcpf(1.0f + e);
                    float th   = fmaf(-2.0f, e * u, 1.0f);
                    float scv  = th * rsq;
                    float orv = ar * scv, oiv = ai * scv;
                    float e2 = orv * orv + oiv * oiv;
                    e2 += __shfl_xor(e2, 1);
                    e2 += __shfl_xor(e2, 2);
                    e2 += __shfl_xor(e2, 4);
                    e2 += __shfl_xor(e2, 8);
                    if (ln15 == 0) atomicAdd(energy + im * 10 + (j - 121), e2);
                }
            }
        }
    }
}

__global__ void k_readout(const float* __restrict__ ws,
                          const float* __restrict__ W,
                          const float* __restrict__ bias,
                          float* __restrict__ out) {
    int i = blockIdx.x * 256 + threadIdx.x;
    if (i < 1280) {
        int b = i / 10, o = i % 10;
        float s = bias[o];
#pragma unroll
        for (int f = 0; f < 10; ++f) {
            float feat = log1pf(ws[WS_ENERGY + b * 10 + f] + 1e-8f);
            s = fmaf(feat, W[o * 10 + f], s);
        }
        out[i] = s;
    }
}

extern "C" void kernel_launch(void* const* d_in, const int* in_sizes, int n_in,
                              void* d_out, int out_size, void* d_ws, size_t ws_size,
                              hipStream_t stream) {
    const float* images = (const float*)d_in[0];
    const float* conn_r = (const float*)d_in[1];
    const float* conn_i = (const float*)d_in[2];
    const float* phase  = (const float*)d_in[3];
    const float* gain   = (const float*)d_in[4];
    const float* W      = (const float*)d_in[5];
    const float* bias   = (const float*)d_in[6];
    float* ws  = (float*)d_ws;
    float* out = (float*)d_out;

    // zero WS_MAX + energy (floats 0..1343) — stream-ordered, capture-safe
    hipMemsetAsync(ws, 0, (WS_ENERGY + 1280) * sizeof(float), stream);
    hipLaunchKernelGGL(k_pre, dim3(189), dim3(256), 0, stream,
                       images, conn_r, conn_i, phase, gain, ws);
    hipLaunchKernelGGL(k_main, dim3(256), dim3(512), 0, stream,
                       images, ws, ws + WS_ENERGY);
    hipLaunchKernelGGL(k_readout, dim3(5), dim3(256), 0, stream, ws, W, bias, out);
}

// Round 13
// 217.704 us; speedup vs baseline: 2.0141x; 1.2398x over previous
//
#include <hip/hip_runtime.h>
#include <cmath>

// PhaseAwareClassifier on MI355X — R30: the l-fold (mirror-symmetric
// columns) — 1.94x algorithmic work reduction.
// R29 post-mortem: SIMD-pair stagger null (222.2 vs 223.5) -> R25 structure
// is issue/latency-saturated at 2/SIMD (VALUBusy 53 + MfmaUtil 37 ~ 90%).
// Before calling roofline, a fresh-eyes algorithm pass found:
//   w_weights[l] = 1 - |l-32|/64 is SYMMETRIC: wl(32-d) == wl(32+d), and
//   the per-column dynamics depend on l ONLY through wl. Columns (32-d,m)
//   and (32+d,m) have bit-identical trajectories. Only 33 unique l in
//   [0..32] need computing; mirrored pairs contribute 2x energy (x+x = 2x
//   exact in fp32; energy order already nondeterministic via atomics).
// Packing: 33 u x 128 img = 4224 wave-tasks (16 cols each). 2048 workers
// (256 blk x 8 waves) -> 2 full rounds + 128 u=32 tasks concentrated in
// blocks 0..15 as FULL 8-wave 3rd rounds (preserves co-residency; solo
// waves would hit R22-style 1/SIMD latency). Wall ~ 3 round-times vs 4.
// Task body = R25/R29 byte-identical (stagger removed: proven null).
// Bit-exact per column; energy weight x2 exact. absmax 0.0078125 expected.
// LDS: conn 82,944 + OBP 73,728 + gsp 576 = 157,248 B -> 1 block/CU.

#define NSTEPS  10
#define INJ_ST  4
#define MT      144          // padded M (9 tiles of 16)
#define NTASK   4224         // 33 unique l x 128 images

typedef __bf16 bf16x8 __attribute__((ext_vector_type(8)));
typedef __bf16 bf16x4 __attribute__((ext_vector_type(4)));
typedef short  short8 __attribute__((ext_vector_type(8)));
typedef float  f32x4  __attribute__((ext_vector_type(4)));

// workspace layout (float offsets)
#define WS_MAX    0          // 1      enc_max (uint-ordered float)
#define WS_ENERGY 64         // 1280   energy[b][10]
#define WS_GSP    2048       // 144    g2q[j] = -0.5*log2(e)*softplus(gain)
#define WS_CONN   4096       // 2 bf16 mats [20][144][8] chunked: Cr, Ci

// fused prep: blocks 0..97 = image absmax; blocks 98.. = conn + gsp tables
__global__ void k_pre(const float* __restrict__ img,
                      const float* __restrict__ cr, const float* __restrict__ ci,
                      const float* __restrict__ phase, const float* __restrict__ gain,
                      float* ws) {
    if (blockIdx.x < 98) {
        __shared__ float sm[256];
        float v = 0.f;
        for (int i = blockIdx.x * 256 + threadIdx.x; i < 128 * 28 * 28; i += 98 * 256)
            v = fmaxf(v, fabsf(img[i]));
        sm[threadIdx.x] = v;
        __syncthreads();
        for (int s = 128; s > 0; s >>= 1) {
            if (threadIdx.x < s) sm[threadIdx.x] = fmaxf(sm[threadIdx.x], sm[threadIdx.x + s]);
            __syncthreads();
        }
        if (threadIdx.x == 0)
            atomicMax((unsigned int*)(ws + WS_MAX), __float_as_uint(sm[0]));
        return;
    }
    int i = (blockIdx.x - 98) * 256 + threadIdx.x;
    __bf16* Cb = (__bf16*)(ws + WS_CONN);
    const int NCE = MT * 160;              // 23040 (m,k) pairs
    if (i < NCE) {
        int m = i / 160, k = i % 160;
        float vr = 0.f, vi = 0.f;
        if (m < 131 && k < 131) {
            float a = cr[k * 131 + m], b = ci[k * 131 + m];
            float ph = phase[m];
            float cp = cosf(ph), sp = sinf(ph);
            vr = a * cp - b * sp;
            vi = a * sp + b * cp;
        }
        int ca = ((k >> 3) * MT + m) * 8 + (k & 7);    // chunked addr
        Cb[ca]       = (__bf16)vr;
        Cb[NCE + ca] = (__bf16)vi;
    } else if (i < NCE + MT) {
        int j = i - NCE;
        float g = 0.f;
        if (j < 131) {
            float x = gain[j];
            g = (x > 20.f) ? x : log1pf(expf(x));  // softplus
        }
        ws[WS_GSP + j] = g * -0.72134754543f;       // -2*log2(e)*g / 4
    }
}

static __device__ __forceinline__ f32x4 MF(bf16x8 a, bf16x8 b, f32x4 c) {
    return __builtin_amdgcn_mfma_f32_16x16x32_bf16(a, b, c, 0, 0, 0);
}
static __device__ __forceinline__ bf16x8 bneg(bf16x8 a) {
    short8 t = __builtin_bit_cast(short8, a) ^ (short8)(short)0x8000;
    return __builtin_bit_cast(bf16x8, t);
}

// one complex 16x16 tile accumulation; order identical to R17..R29.
#define CPAIR(AR, AI, BR, BI, BNI, P)                                  \
    accr[P] = MF(AR, BR,  accr[P]);                                    \
    accr[P] = MF(AI, BNI, accr[P]);                                    \
    acci[P] = MF(AR, BI,  acci[P]);                                    \
    acci[P] = MF(AI, BR,  acci[P]);

__global__ __launch_bounds__(512, 2)
void k_main(const float* __restrict__ img, const float* __restrict__ ws,
            float* __restrict__ energy) {
    __shared__ __bf16 CrL[18 * MT * 8];            // 41,472 B
    __shared__ __bf16 CiL[18 * MT * 8];            // 41,472 B
    __shared__ __bf16 OBP[2][8][18 * 16 * 8];      // 73,728 B  [r/i][wave][...]
    __shared__ float  gspL[144];                   // 576 B
    // total 157,248 B -> 1 block/CU, 8 waves = 2/SIMD (hint matches).

    const int tid  = threadIdx.x;
    const int lane = tid & 63;
    const int ln15 = lane & 15;
    const int quad = lane >> 4;
    const int w    = __builtin_amdgcn_readfirstlane(tid >> 6);  // 0..7

    __bf16* __restrict__ OWr = &OBP[0][w][0];
    __bf16* __restrict__ OWi = &OBP[1][w][0];

    // injection scaling (identical rounding chain to R20..R29)
    const float mx = ws[WS_MAX];
    const float sc = (mx > 1e-8f) ? (1.02f / mx) : 1.02f;   // 0.85*4*0.3

    // stage conn chunks 0..17 + gsp -> LDS (the ONLY barrier in the kernel)
    {
        const int4* srcR = (const int4*)(ws + WS_CONN);
        const int4* srcI = (const int4*)(ws + WS_CONN + (MT * 160 / 2));
        int4* dstR = (int4*)CrL;
        int4* dstI = (int4*)CiL;
        for (int i = tid; i < 2592; i += 512) { dstR[i] = srcR[i]; dstI[i] = srcI[i]; }
        if (tid < 144) gspL[tid] = ws[WS_GSP + tid];
    }
    __syncthreads();                                // conn + gsp staged

    // ---- wave-task loop: T -> (u = T>>7 in 0..32, im = T&127).
    // r=0: u 0..15; r=1: u 16..31; r=2 (blocks 0..15 only): u=32.
    // Each (u, im) covered exactly once. Waves fully independent. ----
#pragma unroll 1
    for (int r = 0; r < 3; ++r) {
        const int T = r * 2048 + blockIdx.x * 8 + w;
        if (T >= NTASK) break;                      // wave-uniform
        const int u  = T >> 7;                      // unique l (0..32)
        const int im = T & 127;
        const float wl  = 1.0f - fabsf((float)u - 32.0f) * (1.0f / 64.0f);
        const float wgt = (u == 0 || u == 32) ? 1.0f : 2.0f;  // mirror count
        const int imgb = im * 784 + (ln15 >> 2) * 28 + (ln15 & 3);

        f32x4 accr[9], acci[9];                     // p = mt
#pragma unroll
        for (int p = 0; p < 9; ++p) { accr[p] = (f32x4)0.f; acci[p] = (f32x4)0.f; }

        // injection: rows j<49 (tiles 0..3)
        auto inj_add = [&]() {
#pragma unroll
            for (int mt = 0; mt < 4; ++mt) {
#pragma unroll
                for (int rr = 0; rr < 4; ++rr) {
                    int j = mt * 16 + quad * 4 + rr;
                    if (j < 49) {
                        int pi = j / 7, pj = j % 7;
                        float px = img[imgb + pi * 112 + pj * 4];
                        float t  = px * sc;
                        accr[mt][rr] = fmaf(t, wl, accr[mt][rr]);
                    }
                }
            }
        };

        // epilogue: out = a * tanh(g*|f|)/|f| (0.25 folded), write own OB
        auto epilogue = [&]() {
#pragma unroll
            for (int mt = 0; mt < 9; ++mt) {
                f32x4 g2v = *(const f32x4*)(gspL + mt * 16 + quad * 4);
                bf16x4 pr, pi;
#pragma unroll
                for (int rr = 0; rr < 4; ++rr) {
                    float ar = accr[mt][rr], ai = acci[mt][rr];
                    float mag2 = fmaf(ar, ar, fmaf(ai, ai, 1.6e-7f));
                    float rsq  = __builtin_amdgcn_rsqf(mag2);
                    float e    = __builtin_amdgcn_exp2f(g2v[rr] * (mag2 * rsq));
                    float uu   = __builtin_amdgcn_rcpf(1.0f + e);
                    float th   = fmaf(-2.0f, e * uu, 1.0f);
                    float scv  = th * rsq;
                    pr[rr] = (__bf16)(ar * scv); pi[rr] = (__bf16)(ai * scv);
                }
                const int off = ((mt * 2 + (quad >> 1)) * 16 + ln15) * 8
                              + (quad & 1) * 4;
                *(bf16x4*)(OWr + off) = pr;
                *(bf16x4*)(OWi + off) = pi;
            }
        };

        inj_add();                                  // t = 0 (out is zero)
        epilogue();                                 // wave-private, no barrier

        // ---- time loop: zero barriers; burst kt body (R25-identical) ----
#pragma unroll 1
        for (int t = 1; t < NSTEPS - 1; ++t) {
#pragma unroll
            for (int p = 0; p < 9; ++p) { accr[p] *= 0.85f; acci[p] *= 0.85f; }
            if (t < INJ_ST) inj_add();

            // t=1: out(0) rows >=49 exactly zero -> kt 0,1 only.
            const int ktEnd = (t == 1) ? 2 : 5;
            // kch 18,19 remap to chunk 17 (zeros both sides). unroll(1): R15.
#pragma unroll 1
            for (int kt = 0; kt < ktEnd; ++kt) {
                const int kch = kt * 4 + quad;
                const int rk  = (kch > 17) ? 17 : kch;
                // ---- load burst: 2 B + 18 A reads, then MFMA block ----
                const int bb  = (rk * 16 + ln15) * 8;
                bf16x8 br = *(const bf16x8*)(OWr + bb);
                bf16x8 bi = *(const bf16x8*)(OWi + bb);
                const int ab = (rk * MT + ln15) * 8;
                bf16x8 ar[9], ai[9];
#pragma unroll
                for (int mt = 0; mt < 9; ++mt) {
                    ar[mt] = *(const bf16x8*)(CrL + ab + mt * 128);
                    ai[mt] = *(const bf16x8*)(CiL + ab + mt * 128);
                }
                bf16x8 bn = bneg(bi);
#pragma unroll
                for (int mt = 0; mt < 9; ++mt) {
                    CPAIR(ar[mt], ai[mt], br, bi, bn, mt)
                }
            }
            epilogue();                             // wave-private, no barrier
        }

        // ---- t = 9: only rows 121..130 (tiles 7,8) feed energy ----
        accr[7] *= 0.85f; acci[7] *= 0.85f;
        accr[8] *= 0.85f; acci[8] *= 0.85f;
#pragma unroll 1
        for (int kt = 0; kt < 5; ++kt) {
            const int kch = kt * 4 + quad;
            const int rk  = (kch > 17) ? 17 : kch;
            const int bb  = (rk * 16 + ln15) * 8;
            bf16x8 br = *(const bf16x8*)(OWr + bb);
            bf16x8 bi = *(const bf16x8*)(OWi + bb);
            const int ab = (rk * MT + ln15) * 8;
            bf16x8 ar7 = *(const bf16x8*)(CrL + ab + 7 * 128);
            bf16x8 ai7 = *(const bf16x8*)(CiL + ab + 7 * 128);
            bf16x8 ar8 = *(const bf16x8*)(CrL + ab + 8 * 128);
            bf16x8 ai8 = *(const bf16x8*)(CiL + ab + 8 * 128);
            bf16x8 bn = bneg(bi);
            CPAIR(ar7, ai7, br, bi, bn, 7)
            CPAIR(ar8, ai8, br, bi, bn, 8)
        }

        // ---- energy: per-lane |out|^2, quad shfl-reduce over 16 cols,
        // one atomicAdd per (j), weighted by mirror multiplicity ----
#pragma unroll
        for (int mt = 7; mt < 9; ++mt) {
#pragma unroll
            for (int rr = 0; rr < 4; ++rr) {
                int j = mt * 16 + quad * 4 + rr;
                if (j >= 121 && j <= 130) {
                    float ar = accr[mt][rr], ai = acci[mt][rr];
                    float mag2 = fmaf(ar, ar, fmaf(ai, ai, 1.6e-7f));
                    float rsq  = __builtin_amdgcn_rsqf(mag2);
                    float e    = __builtin_amdgcn_exp2f(gspL[j] * (mag2 * rsq));
                    float uu   = __builtin_amdgcn_rcpf(1.0f + e);
                    float th   = fmaf(-2.0f, e * uu, 1.0f);
                    float scv  = th * rsq;
                    float orv = ar * scv, oiv = ai * scv;
                    float e2 = orv * orv + oiv * oiv;
                    e2 += __shfl_xor(e2, 1);
                    e2 += __shfl_xor(e2, 2);
                    e2 += __shfl_xor(e2, 4);
                    e2 += __shfl_xor(e2, 8);
                    if (ln15 == 0)
                        atomicAdd(energy + im * 10 + (j - 121), e2 * wgt);
                }
            }
        }
    }
}

__global__ void k_readout(const float* __restrict__ ws,
                          const float* __restrict__ W,
                          const float* __restrict__ bias,
                          float* __restrict__ out) {
    int i = blockIdx.x * 256 + threadIdx.x;
    if (i < 1280) {
        int b = i / 10, o = i % 10;
        float s = bias[o];
#pragma unroll
        for (int f = 0; f < 10; ++f) {
            float feat = log1pf(ws[WS_ENERGY + b * 10 + f] + 1e-8f);
            s = fmaf(feat, W[o * 10 + f], s);
        }
        out[i] = s;
    }
}

extern "C" void kernel_launch(void* const* d_in, const int* in_sizes, int n_in,
                              void* d_out, int out_size, void* d_ws, size_t ws_size,
                              hipStream_t stream) {
    const float* images = (const float*)d_in[0];
    const float* conn_r = (const float*)d_in[1];
    const float* conn_i = (const float*)d_in[2];
    const float* phase  = (const float*)d_in[3];
    const float* gain   = (const float*)d_in[4];
    const float* W      = (const float*)d_in[5];
    const float* bias   = (const float*)d_in[6];
    float* ws  = (float*)d_ws;
    float* out = (float*)d_out;

    // zero WS_MAX + energy (floats 0..1343) — stream-ordered, capture-safe
    hipMemsetAsync(ws, 0, (WS_ENERGY + 1280) * sizeof(float), stream);
    hipLaunchKernelGGL(k_pre, dim3(189), dim3(256), 0, stream,
                       images, conn_r, conn_i, phase, gain, ws);
    hipLaunchKernelGGL(k_main, dim3(256), dim3(512), 0, stream,
                       images, ws, ws + WS_ENERGY);
    hipLaunchKernelGGL(k_readout, dim3(5), dim3(256), 0, stream, ws, W, bias, out);
}